// Round 17
// baseline (288.042 us; speedup 1.0000x reference)
//
#include <hip/hip_runtime.h>
#include <cmath>
#include <algorithm>

#define NPATH   11
#define NNODES  10000
#define NEDGES  160000
#define EB      16
#define INDIM   144

// ================= compile-time Wigner-3j construction =================
constexpr double csqrt_(double x){
  if (x <= 0.0) return 0.0;
  double g = x >= 1.0 ? x : 1.0;
  for (int i = 0; i < 48; ++i) g = 0.5*(g + x/g);
  return g;
}
constexpr double factd_(int n){ double r = 1.0; for (int i = 2; i <= n; ++i) r *= (double)i; return r; }
constexpr int imax2_(int a,int b){ return a>b?a:b; }
constexpr int imin2_(int a,int b){ return a<b?a:b; }

constexpr double su2_cg_ce(int j1,int m1,int j2,int m2,int j3,int m3){
  if (m3 != m1 + m2) return 0.0;
  const int vmin = imax2_(imax2_(-j1 + j2 + m3, -j1 + m1), 0);
  const int vmax = imin2_(imin2_(j2 + j3 + m1, j3 - j1 + j2), j3 + m3);
  const double C = csqrt_((2.0*j3 + 1.0)
      * factd_(j3 + j1 - j2) * factd_(j3 - j1 + j2) * factd_(j1 + j2 - j3) / factd_(j1 + j2 + j3 + 1)
      * factd_(j3 + m3) * factd_(j3 - m3)
      / (factd_(j1 - m1) * factd_(j1 + m1) * factd_(j2 - m2) * factd_(j2 + m2)));
  double S = 0.0;
  for (int v = vmin; v <= vmax; ++v){
    const double sgn = ((v + j2 + m2) & 1) ? -1.0 : 1.0;
    S += sgn / factd_(v) * factd_(j2 + j3 + m1 - v) * factd_(j1 - m1 + v)
         / factd_(j3 - j1 + j2 - v) / factd_(j3 + m3 - v) / factd_(v + j1 - j2 - m3);
  }
  return C * S;
}

struct QM { double re[25]; double im[25]; };
constexpr QM qmat_ce(int l){
  QM q{};
  const int n = 2*l + 1;
  const double is2 = 1.0 / csqrt_(2.0);
  for (int m = -l; m < 0; ++m){
    q.re[(l+m)*n + (l-m)] = is2;
    q.im[(l+m)*n + (l+m)] = -is2;
  }
  q.re[l*n + l] = 1.0;
  for (int m = 1; m <= l; ++m){
    const double s = (m & 1) ? -1.0 : 1.0;
    q.re[(l+m)*n + (l+m)] = s * is2;
    q.im[(l+m)*n + (l-m)] = s * is2;
  }
  const double phr = (l==0) ? 1.0 : (l==1 ? 0.0 : -1.0);
  const double phi = (l==1) ? -1.0 : 0.0;
  for (int i = 0; i < n*n; ++i){
    const double r  = q.re[i]*phr - q.im[i]*phi;
    const double im = q.re[i]*phi + q.im[i]*phr;
    q.re[i] = r; q.im[i] = im;
  }
  return q;
}

struct W3R { double v[125]; };
template<int L1,int L2,int L3>
constexpr W3R w3j_ce(){
  constexpr int n1 = 2*L1+1, n2 = 2*L2+1, n3 = 2*L3+1;
  const QM q1 = qmat_ce(L1), q2 = qmat_ce(L2), q3 = qmat_ce(L3);
  double C[n1][n2]{};
  for (int i = 0; i < n1; ++i)
    for (int k = 0; k < n2; ++k){
      const int nn = (i - L1) + (k - L2) + L3;
      C[i][k] = (nn >= 0 && nn < n3) ? su2_cg_ce(L1, i-L1, L2, k-L2, L3, nn-L3) : 0.0;
    }
  W3R out{};
  double norm = 0.0;
  for (int j = 0; j < n1; ++j)
    for (int lq = 0; lq < n2; ++lq)
      for (int m = 0; m < n3; ++m){
        double sre = 0.0;
        for (int i = 0; i < n1; ++i)
          for (int k = 0; k < n2; ++k){
            if (C[i][k] == 0.0) continue;
            const int nn = (i - L1) + (k - L2) + L3;
            const double ar = q1.re[i*n1+j],  ai = q1.im[i*n1+j];
            const double br = q2.re[k*n2+lq], bi = q2.im[k*n2+lq];
            const double cr = q3.re[nn*n3+m], ci = q3.im[nn*n3+m];
            const double abr = ar*br - ai*bi;
            const double abi = ar*bi + ai*br;
            sre += (abr*cr + abi*ci) * C[i][k];
          }
        out.v[(j*n2+lq)*n3+m] = sre;
        norm += sre*sre;
      }
  norm = csqrt_(norm);
  for (int i = 0; i < n1*n2*n3; ++i) out.v[i] /= norm;
  return out;
}

constexpr W3R W_p0  = w3j_ce<0,0,0>();
constexpr W3R W_p1  = w3j_ce<0,1,1>();
constexpr W3R W_p2  = w3j_ce<0,2,2>();
constexpr W3R W_p3  = w3j_ce<1,0,1>();
constexpr W3R W_p4  = w3j_ce<1,1,0>();
constexpr W3R W_p5  = w3j_ce<1,1,2>();
constexpr W3R W_p6  = w3j_ce<1,2,1>();
constexpr W3R W_p7  = w3j_ce<2,0,2>();
constexpr W3R W_p8  = w3j_ce<2,1,1>();
constexpr W3R W_p9  = w3j_ce<2,2,0>();
constexpr W3R W_p10 = w3j_ce<2,2,2>();

struct CoefArr { float c[363]; };
constexpr float snap_(double v){ return (v < 1e-9 && v > -1e-9) ? 0.0f : (float)v; }
constexpr CoefArr build_ck(){
  CoefArr K{};
  const W3R* W[NPATH] = {&W_p0,&W_p1,&W_p2,&W_p3,&W_p4,&W_p5,&W_p6,&W_p7,&W_p8,&W_p9,&W_p10};
  const int SZ[NPATH]  = {1,9,25,9,9,45,45,25,45,25,125};
  const int PL3[NPATH] = {0,1,2,1,0,2,1,2,1,0,2};
  const double FAN[3]  = {48.0, 64.0, 64.0};
  int off = 0;
  for (int p = 0; p < NPATH; ++p){
    const double alpha = csqrt_((double)(2*PL3[p]+1)) / csqrt_(FAN[PL3[p]]);
    for (int i = 0; i < SZ[p]; ++i) K.c[off + i] = snap_(W[p]->v[i] * alpha);
    off += SZ[p];
  }
  return K;
}
inline constexpr CoefArr CK = build_ck();

// ---------------- device helpers ----------------
typedef __attribute__((ext_vector_type(8))) short bf16x8;
typedef __attribute__((ext_vector_type(4))) float f32x4;

__device__ __forceinline__ float silu_f(float v){ return v / (1.0f + expf(-v)); }
__device__ __forceinline__ float b2f(unsigned short u){
  union { unsigned i; float f; } x; x.i = ((unsigned)u) << 16; return x.f;
}
__device__ __forceinline__ unsigned short f2b(float f){
  union { float f; unsigned i; } x; x.f = f;
  unsigned r = x.i + 0x7FFFu + ((x.i >> 16) & 1u);
  return (unsigned short)(r >> 16);
}

// ---- LDS layout (EB=16, f32 tmp, THREE CG/consume rounds sharing 18 slots):
// sh f32 [9][16] | src/dst | tmp f32 [18*16][16] (emb + emit stage alias)
// | x1 bf16 [144][18] | h bf16 [16][72].  Total 26624 B -> 6 blocks/CU
// at natural VGPR 64 (cap 128 via (256,4): NO forced squeeze -> no spill).
// Rounds: A = D3 in {1,3} (15 slots); B1 = paths 2,5 (10); B2 = paths 7,10 (10).
#define O_SH     0        // float idx
#define O_SD     144      // float idx (src[16], dst[16])
#define O_TPF    176      // float idx of tmp f32 [18*16][16]; emb+stage alias
#define X16_OFF  9568     // short idx of x1 bf16 [144][18]
#define H_OFF    12160    // short idx of h bf16 [16][72]
#define S_TOT    6656     // floats = 26624 B
#define XPAD 18
#define HPAD 72

__device__ __forceinline__ bf16x8 load_h_frag(const unsigned short* h16, int row, int kbase, int rg){
  return *(const bf16x8*)(h16 + row*HPAD + kbase + rg*8);
}

// ---- CG for one path: coefficient literals from CK (zeros fold away) ----
template<int D1,int D2,int D3,int SB,int COFF,int XB,int SHO>
__device__ __forceinline__ void cg_path(float* tpf,
    const float (&xv)[9], const float (&sv)[9], int u, int e)
{
  float a0[D3];
  #pragma unroll
  for (int k = 0; k < D3; ++k) a0[k] = 0.0f;
  #pragma unroll
  for (int i = 0; i < D1; ++i){
    #pragma unroll
    for (int j = 0; j < D2; ++j){
      const float p0 = xv[XB+i] * sv[SHO+j];
      #pragma unroll
      for (int k = 0; k < D3; ++k){
        const float cf = CK.c[COFF + (i*D2 + j)*D3 + k];   // compile-time constant
        if (cf != 0.0f) a0[k] = fmaf(cf, p0, a0[k]);
      }
    }
  }
  #pragma unroll
  for (int k = 0; k < D3; ++k)
    tpf[((SB + k)*16 + u)*16 + e] = a0[k];
}

// ---- consume: ONE shared body per D3-group, runtime path loop (code-size) ----
static __device__ const int gA1P[3] = {0,4,9},   gA1S[3] = {0,1,2};
static __device__ const int gA3P[4] = {1,3,6,8}, gA3S[4] = {3,6,9,12};
static __device__ const int gB1P[2] = {2,5},     gB1S[2] = {0,5};
static __device__ const int gB2P[2] = {7,10},    gB2S[2] = {0,5};

template<int D3,int QB,int NP,int NQ>
__device__ __forceinline__ void consume_group(
    const int* __restrict__ plist, const int* __restrict__ sblist,
    const unsigned short* __restrict__ w3B, const float* __restrict__ b3,
    const float* tpf,
    const bf16x8& ha0, const bf16x8& ha1,
    int ch, int j2, int lw, int rg, float (&acc)[NQ][4])
{
  const int lane8 = (rg*16 + lw)*8;
  #pragma unroll 1
  for (int pi = 0; pi < NP; ++pi){
    const int P  = plist[pi];
    const int SB = sblist[pi];
    const unsigned short* wbase = w3B + (size_t)((P*2 + ch)*8 + j2*4)*1024 + lane8;
    const float* bcol = b3 + P*256 + ch*128 + j2*64 + lw;
    const float* tbase = tpf + (SB*16 + ch*8 + j2*4)*16 + rg*4;

    bf16x8 wf0[4], wf1[4];
    float bvv[4];
    #pragma unroll
    for (int jt = 0; jt < 4; ++jt){
      wf0[jt] = *(const bf16x8*)(wbase + jt*1024);
      wf1[jt] = *(const bf16x8*)(wbase + jt*1024 + 512);
      bvv[jt] = bcol[jt*16];
    }
    #pragma unroll
    for (int jt = 0; jt < 4; ++jt){
      f32x4 c = {bvv[jt], bvv[jt], bvv[jt], bvv[jt]};
      c = __builtin_amdgcn_mfma_f32_16x16x32_bf16(ha0, wf0[jt], c, 0, 0, 0);
      c = __builtin_amdgcn_mfma_f32_16x16x32_bf16(ha1, wf1[jt], c, 0, 0, 0);
      #pragma unroll
      for (int k = 0; k < D3; ++k){
        const f32x4 tv = *(const f32x4*)(tbase + jt*16 + k*256);
        acc[QB+k][0] = fmaf(tv[0], c[0], acc[QB+k][0]);
        acc[QB+k][1] = fmaf(tv[1], c[1], acc[QB+k][1]);
        acc[QB+k][2] = fmaf(tv[2], c[2], acc[QB+k][2]);
        acc[QB+k][3] = fmaf(tv[3], c[3], acc[QB+k][3]);
      }
    }
  }
}

template<bool TWOPASS>
__global__ __launch_bounds__(256, 4)
void e3_fused(
    const float* __restrict__ f_in, const float* __restrict__ pos,
    const int*   __restrict__ batch,
    const int*   __restrict__ esrc, const int* __restrict__ edst,
    const float* __restrict__ eshift, const float* __restrict__ cell,
    const float* __restrict__ w0, const float* __restrict__ b0,
    const float* __restrict__ b1, const float* __restrict__ b2,
    const float* __restrict__ b3, const unsigned short* __restrict__ wT,
    float* __restrict__ msg_or_out)
{
  __shared__ float S[S_TOT];
  float* tpf = S + O_TPF;
  unsigned short* x16  = (unsigned short*)S + X16_OFF;
  unsigned short* h16  = (unsigned short*)S + H_OFF;
  int* s_src = (int*)(S + O_SD);
  int* s_dst = s_src + EB;
  const int t = threadIdx.x;
  const int e0 = blockIdx.x * EB;
  const unsigned short* w3B = wT;
  const unsigned short* w1T = wT + 180224;
  const unsigned short* w2T = wT + 184320;
  float* emb = tpf;    // f32 [8][16], aliases tmp (dead before CG writes)

  // ---- geometry / SH / radial (one thread per edge) ----
  if (t < EB){
    const int eg  = e0 + t;
    const int src = esrc[eg];
    const int dst = edst[eg];
    s_src[t] = src; s_dst[t] = dst;
    const int g = batch[src];
    const float sx = eshift[eg*3+0], sy = eshift[eg*3+1], sz = eshift[eg*3+2];
    const float* cg = cell + g*9;
    float vx = pos[dst*3+0] - pos[src*3+0] + sx*cg[0] + sy*cg[3] + sz*cg[6];
    float vy = pos[dst*3+1] - pos[src*3+1] + sx*cg[1] + sy*cg[4] + sz*cg[7];
    float vz = pos[dst*3+2] - pos[src*3+2] + sx*cg[2] + sy*cg[5] + sz*cg[8];
    float r  = sqrtf(vx*vx + vy*vy + vz*vz + 1e-12f);
    float inv = 1.0f / r;
    float x = vx*inv, y = vy*inv, z = vz*inv;
    const float s3 = 1.7320508075688772f, s5 = 2.23606797749979f, s15 = 3.872983346207417f;
    S[O_SH + 0*16 + t] = 1.0f;
    S[O_SH + 1*16 + t] = s3 * y;
    S[O_SH + 2*16 + t] = s3 * z;
    S[O_SH + 3*16 + t] = s3 * x;
    S[O_SH + 4*16 + t] = s15 * x * y;
    S[O_SH + 5*16 + t] = s15 * y * z;
    S[O_SH + 6*16 + t] = 0.5f * s5 * (3.0f*z*z - 1.0f);
    S[O_SH + 7*16 + t] = s15 * x * z;
    S[O_SH + 8*16 + t] = 0.5f * s15 * (x*x - y*y);
    float xr   = fminf(fmaxf(r * (1.0f/6.0f), 0.0f), 1.0f);
    float mask = (r <= 6.0f) ? 2.8284271247461903f : 0.0f;
    #pragma unroll
    for (int b = 0; b < 8; ++b){
      float d = (xr - (float)b * (1.0f/7.0f)) * 7.0f;
      emb[b*16 + t] = mask * expf(-0.5f * d * d);
    }
  }
  __syncthreads();

  // ---- gather x1 -> bf16 transposed [c][e] ----
  for (int idx = t; idx < EB*36; idx += 256){
    const int e = idx / 36, c4 = idx - e*36;
    const float4 v = *(const float4*)(f_in + (size_t)s_src[e]*INDIM + c4*4);
    x16[(c4*4 + 0)*XPAD + e] = f2b(v.x);
    x16[(c4*4 + 1)*XPAD + e] = f2b(v.y);
    x16[(c4*4 + 2)*XPAD + e] = f2b(v.z);
    x16[(c4*4 + 3)*XPAD + e] = f2b(v.w);
  }

  const int lane = t & 63, wid = t >> 6;
  const int lw = lane & 15, rg = lane >> 4;

  // ---- MLP layer 0 (8 -> 64), VALU f32; output bf16 to h ----
  {
    const int o = t & 63, egr = t >> 6;   // each thread: 4 edges
    float s[4];
    #pragma unroll
    for (int e4 = 0; e4 < 4; ++e4) s[e4] = b0[o];
    #pragma unroll
    for (int c = 0; c < 8; ++c){
      const float wv = w0[c*64 + o];
      #pragma unroll
      for (int e4 = 0; e4 < 4; ++e4)
        s[e4] = fmaf(emb[c*16 + egr*4 + e4], wv, s[e4]);
    }
    #pragma unroll
    for (int e4 = 0; e4 < 4; ++e4) h16[(egr*4 + e4)*HPAD + o] = f2b(silu_f(s[e4]));
  }
  __syncthreads();

  // ---- MLP layers 1,2 via MFMA: C[16 e][64 o], 4 tiles over 4 waves ----
  #pragma unroll
  for (int layer = 0; layer < 2; ++layer){
    const unsigned short* wLT = layer ? w2T : w1T;
    const float* bL = layer ? b2 : b1;
    const bf16x8 a0 = load_h_frag(h16, lw, 0, rg);
    const bf16x8 a1 = load_h_frag(h16, lw, 32, rg);
    const int o = wid*16 + lw;
    const bf16x8 bf0 = *(const bf16x8*)(wLT + o*64 + rg*8);
    const bf16x8 bf1 = *(const bf16x8*)(wLT + o*64 + 32 + rg*8);
    const float bv = bL[o];
    f32x4 c = {bv, bv, bv, bv};
    c = __builtin_amdgcn_mfma_f32_16x16x32_bf16(a0, bf0, c, 0, 0, 0);
    c = __builtin_amdgcn_mfma_f32_16x16x32_bf16(a1, bf1, c, 0, 0, 0);
    __syncthreads();   // all frag reads done before overwrite
    #pragma unroll
    for (int i = 0; i < 4; ++i)
      h16[(rg*4 + i)*HPAD + wid*16 + lw] = f2b(silu_f(c[i]));
    __syncthreads();
  }

  // ---- A-fragments of final h (held through CG + consume) ----
  const int ch = wid & 1, j2 = wid >> 1;
  const bf16x8 ha0 = load_h_frag(h16, lw, 0, rg);
  const bf16x8 ha1 = load_h_frag(h16, lw, 32, rg);

  const int u_cg = t >> 4, e_cg = t & 15;
  float sv[9], xv[9];
  #pragma unroll
  for (int j = 0; j < 9; ++j) sv[j] = S[O_SH + j*16 + e_cg];
  #pragma unroll
  for (int ri = 0; ri < 9; ++ri)
    xv[ri] = b2f(x16[(ri*16 + u_cg)*XPAD + e_cg]);

  // ================= round A: D3 in {1,3} paths, 15 tmp slots =================
  //      <D1,D2,D3, SB, COFF, XB, SHO>
  cg_path<1,1,1,  0,   0, 0, 0>(tpf, xv, sv, u_cg, e_cg);   // path 0
  cg_path<3,3,1,  1,  44, 1, 1>(tpf, xv, sv, u_cg, e_cg);   // path 4
  cg_path<5,5,1,  2, 213, 4, 4>(tpf, xv, sv, u_cg, e_cg);   // path 9
  cg_path<1,3,3,  3,   1, 0, 1>(tpf, xv, sv, u_cg, e_cg);   // path 1
  cg_path<3,1,3,  6,  35, 1, 0>(tpf, xv, sv, u_cg, e_cg);   // path 3
  cg_path<3,5,3,  9,  98, 1, 4>(tpf, xv, sv, u_cg, e_cg);   // path 6
  cg_path<5,3,3, 12, 168, 4, 1>(tpf, xv, sv, u_cg, e_cg);   // path 8
  __syncthreads();   // tmp A complete

  float accA[4][4];
  #pragma unroll
  for (int q = 0; q < 4; ++q)
    #pragma unroll
    for (int i = 0; i < 4; ++i) accA[q][i] = 0.0f;

  consume_group<1,0,3,4>(gA1P, gA1S, w3B, b3, tpf, ha0, ha1, ch, j2, lw, rg, accA);
  consume_group<3,1,4,4>(gA3P, gA3S, w3B, b3, tpf, ha0, ha1, ch, j2, lw, rg, accA);
  __syncthreads();   // tmp A dead

  float accB[5][4];
  #pragma unroll
  for (int q = 0; q < 5; ++q)
    #pragma unroll
    for (int i = 0; i < 4; ++i) accB[q][i] = 0.0f;

  // ================= round B1: paths 2,5 (D3=5), 10 tmp slots =================
  cg_path<1,5,5,  0,  10, 0, 4>(tpf, xv, sv, u_cg, e_cg);   // path 2
  cg_path<3,3,5,  5,  53, 1, 1>(tpf, xv, sv, u_cg, e_cg);   // path 5
  __syncthreads();   // tmp B1 complete

  consume_group<5,0,2,5>(gB1P, gB1S, w3B, b3, tpf, ha0, ha1, ch, j2, lw, rg, accB);
  __syncthreads();   // tmp B1 dead

  // ================= round B2: paths 7,10 (D3=5), 10 tmp slots =================
  cg_path<5,1,5,  0, 143, 4, 0>(tpf, xv, sv, u_cg, e_cg);   // path 7
  cg_path<5,5,5,  5, 238, 4, 4>(tpf, xv, sv, u_cg, e_cg);   // path 10
  __syncthreads();   // tmp B2 complete

  consume_group<5,0,2,5>(gB2P, gB2S, w3B, b3, tpf, ha0, ha1, ch, j2, lw, rg, accB);
  __syncthreads();   // tmp dead; staging region free

  // ---- emit: 4-wave sequential reduction into stage, then coalesced store ----
  if (TWOPASS){
    float* stage = tpf;   // [16 e][144] f32, aliases tmp
    if (wid == 0){
      #pragma unroll
      for (int q = 0; q < 4; ++q)
        #pragma unroll
        for (int i = 0; i < 4; ++i)
          stage[(rg*4 + i)*INDIM + q*16 + lw] = accA[q][i];
      #pragma unroll
      for (int q = 0; q < 5; ++q)
        #pragma unroll
        for (int i = 0; i < 4; ++i)
          stage[(rg*4 + i)*INDIM + (q + 4)*16 + lw] = accB[q][i];
    }
    __syncthreads();
    #pragma unroll
    for (int w = 1; w < 4; ++w){
      if (wid == w){
        #pragma unroll
        for (int q = 0; q < 4; ++q)
          #pragma unroll
          for (int i = 0; i < 4; ++i)
            stage[(rg*4 + i)*INDIM + q*16 + lw] += accA[q][i];
        #pragma unroll
        for (int q = 0; q < 5; ++q)
          #pragma unroll
          for (int i = 0; i < 4; ++i)
            stage[(rg*4 + i)*INDIM + (q + 4)*16 + lw] += accB[q][i];
      }
      __syncthreads();
    }
    for (int idx = t; idx < EB*36; idx += 256){
      const int e = idx / 36, c4 = idx - e*36;
      *(float4*)(msg_or_out + (size_t)(e0 + e)*INDIM + c4*4) =
          *(const float4*)(stage + e*INDIM + c4*4);
    }
  } else {
    #pragma unroll
    for (int i = 0; i < 4; ++i){
      const int e = rg*4 + i;
      float* op = msg_or_out + (size_t)s_dst[e]*INDIM + lw;
      #pragma unroll
      for (int q = 0; q < 4; ++q) atomicAdd(op + q*16, accA[q][i]);
      #pragma unroll
      for (int q = 0; q < 5; ++q) atomicAdd(op + (q + 4)*16, accB[q][i]);
    }
  }
}

// ---------------- weight conversion ----------------
__device__ __forceinline__ unsigned short f2b_dev(float f){
  union { float f; unsigned i; } x; x.f = f;
  unsigned r = x.i + 0x7FFFu + ((x.i >> 16) & 1u);
  return (unsigned short)(r >> 16);
}
__global__ __launch_bounds__(256)
void w_cvt(const float* __restrict__ w3, const float* __restrict__ w1,
           const float* __restrict__ w2, unsigned short* __restrict__ wT){
  const int id = blockIdx.x*256 + threadIdx.x;
  if (id < 180224){
    const int tile = id >> 10, rem = id & 1023;
    const int P = tile >> 4, ch = (tile >> 3) & 1, jq = tile & 7;
    const int half = rem >> 9, rg = (rem >> 7) & 3, lw = (rem >> 3) & 15, kk = rem & 7;
    const int n = P*256 + ch*128 + jq*16 + lw;
    const int k = half*32 + rg*8 + kk;
    wT[id] = f2b_dev(w3[(size_t)k*2816 + n]);
  } else if (id < 184320){
    const int j = id - 180224; const int o = j >> 6, c = j & 63;
    wT[id] = f2b_dev(w1[c*64 + o]);
  } else if (id < 188416){
    const int j = id - 184320; const int o = j >> 6, c = j & 63;
    wT[id] = f2b_dev(w2[c*64 + o]);
  }
}

// ---------------- scatter infrastructure ----------------
__global__ __launch_bounds__(256)
void e3_hist(const int* __restrict__ edst, int* __restrict__ cnt){
  int e = blockIdx.x*256 + threadIdx.x;
  if (e < NEDGES) atomicAdd(&cnt[edst[e]], 1);
}

__global__ __launch_bounds__(1024)
void e3_scan(const int* __restrict__ cnt, int* __restrict__ offs, int* __restrict__ cursor, int n){
  __shared__ int buf[1024];
  __shared__ int carry;
  const int t = threadIdx.x;
  if (t == 0) carry = 0;
  __syncthreads();
  for (int base = 0; base < n; base += 1024){
    int v = (base + t < n) ? cnt[base + t] : 0;
    buf[t] = v;
    __syncthreads();
    for (int d = 1; d < 1024; d <<= 1){
      int x = (t >= d) ? buf[t - d] : 0;
      __syncthreads();
      buf[t] += x;
      __syncthreads();
    }
    const int base_c = carry;
    if (base + t < n){
      const int ex = base_c + buf[t] - v;
      offs[base + t]   = ex;
      cursor[base + t] = ex;
    }
    __syncthreads();
    if (t == 1023) carry = base_c + buf[1023];
    __syncthreads();
  }
  if (t == 0) offs[n] = carry;
}

__global__ __launch_bounds__(256)
void e3_fill(const int* __restrict__ edst, int* __restrict__ cursor, int* __restrict__ eidx){
  int e = blockIdx.x*256 + threadIdx.x;
  if (e < NEDGES){
    int pos = atomicAdd(&cursor[edst[e]], 1);
    eidx[pos] = e;
  }
}

__global__ __launch_bounds__(192)
void e3_reduce(const float* __restrict__ msg, const int* __restrict__ offs,
               const int* __restrict__ eidx, float* __restrict__ out){
  const int nid = blockIdx.x;
  const int t = threadIdx.x;
  if (t >= 144) return;
  const int beg = offs[nid], end = offs[nid + 1];
  float a0 = 0.f, a1 = 0.f, a2 = 0.f, a3 = 0.f;
  int i = beg;
  for (; i + 4 <= end; i += 4){
    const int i0 = eidx[i], i1 = eidx[i+1], i2 = eidx[i+2], i3 = eidx[i+3];
    a0 += msg[(size_t)i0*INDIM + t];
    a1 += msg[(size_t)i1*INDIM + t];
    a2 += msg[(size_t)i2*INDIM + t];
    a3 += msg[(size_t)i3*INDIM + t];
  }
  for (; i < end; ++i) a0 += msg[(size_t)eidx[i]*INDIM + t];
  const float deg = (float)(end - beg);
  out[(size_t)nid*INDIM + t] = (a0 + a1 + a2 + a3) / fmaxf(deg, 1.0f);
}

__global__ __launch_bounds__(256)
void e3_div(float* __restrict__ out, const int* __restrict__ cnt, int n){
  int i = blockIdx.x*256 + threadIdx.x;
  if (i < n){
    float c = (float)cnt[i / INDIM];
    out[i] /= fmaxf(c, 1.0f);
  }
}

extern "C" void kernel_launch(void* const* d_in, const int* in_sizes, int n_in,
                              void* d_out, int out_size, void* d_ws, size_t ws_size,
                              hipStream_t stream)
{
  const float* f_in   = (const float*)d_in[0];
  const float* pos    = (const float*)d_in[1];
  const int*   batch  = (const int*)  d_in[3];
  const int*   esrc   = (const int*)  d_in[4];
  const int*   edst   = (const int*)  d_in[5];
  const float* eshift = (const float*)d_in[6];
  const float* cell   = (const float*)d_in[7];
  const float* w0 = (const float*)d_in[8];  const float* b0 = (const float*)d_in[9];
  const float* w1 = (const float*)d_in[10]; const float* b1 = (const float*)d_in[11];
  const float* w2 = (const float*)d_in[12]; const float* b2 = (const float*)d_in[13];
  const float* w3 = (const float*)d_in[14]; const float* b3 = (const float*)d_in[15];
  float* out = (float*)d_out;

  const size_t need = (1u << 20) + (size_t)NEDGES * INDIM * sizeof(float);
  const bool twopass = ws_size >= need;

  if (twopass){
    int* cnt_i  = (int*)d_ws;
    int* offs   = (int*)d_ws + 16384;
    int* cursor = (int*)d_ws + 32768;
    int* eidx   = (int*)d_ws + 49152;
    float* msg  = (float*)((char*)d_ws + (1u << 20));
    unsigned short* wT = (unsigned short*)d_out;   // dead until e3_reduce overwrites

    w_cvt<<<736, 256, 0, stream>>>(w3, w1, w2, wT);
    hipMemsetAsync(cnt_i, 0, 10240 * sizeof(int), stream);
    e3_hist<<<(NEDGES + 255)/256, 256, 0, stream>>>(edst, cnt_i);
    e3_scan<<<1, 1024, 0, stream>>>(cnt_i, offs, cursor, NNODES);
    e3_fill<<<(NEDGES + 255)/256, 256, 0, stream>>>(edst, cursor, eidx);
    e3_fused<true><<<NEDGES/EB, 256, 0, stream>>>(
        f_in, pos, batch, esrc, edst, eshift, cell,
        w0, b0, b1, b2, b3, wT, msg);
    e3_reduce<<<NNODES, 192, 0, stream>>>(msg, offs, eidx, out);
  } else {
    unsigned short* wT = (unsigned short*)d_ws;            // 376832 B
    int* cnt_i = (int*)((char*)d_ws + 376832);

    w_cvt<<<736, 256, 0, stream>>>(w3, w1, w2, wT);
    hipMemsetAsync(cnt_i, 0, NNODES * sizeof(int), stream);
    e3_hist<<<(NEDGES + 255)/256, 256, 0, stream>>>(edst, cnt_i);
    hipMemsetAsync(d_out, 0, (size_t)out_size * sizeof(float), stream);
    e3_fused<false><<<NEDGES/EB, 256, 0, stream>>>(
        f_in, pos, batch, esrc, edst, eshift, cell,
        w0, b0, b1, b2, b3, wT, out);
    e3_div<<<(out_size + 255)/256, 256, 0, stream>>>(out, cnt_i, out_size);
  }
}

// Round 18
// 275.411 us; speedup vs baseline: 1.0459x; 1.0459x over previous
//
#include <hip/hip_runtime.h>
#include <cmath>
#include <algorithm>

#define NPATH   11
#define NNODES  10000
#define NEDGES  160000
#define EB      16
#define INDIM   144

// ================= compile-time Wigner-3j construction =================
constexpr double csqrt_(double x){
  if (x <= 0.0) return 0.0;
  double g = x >= 1.0 ? x : 1.0;
  for (int i = 0; i < 48; ++i) g = 0.5*(g + x/g);
  return g;
}
constexpr double factd_(int n){ double r = 1.0; for (int i = 2; i <= n; ++i) r *= (double)i; return r; }
constexpr int imax2_(int a,int b){ return a>b?a:b; }
constexpr int imin2_(int a,int b){ return a<b?a:b; }

constexpr double su2_cg_ce(int j1,int m1,int j2,int m2,int j3,int m3){
  if (m3 != m1 + m2) return 0.0;
  const int vmin = imax2_(imax2_(-j1 + j2 + m3, -j1 + m1), 0);
  const int vmax = imin2_(imin2_(j2 + j3 + m1, j3 - j1 + j2), j3 + m3);
  const double C = csqrt_((2.0*j3 + 1.0)
      * factd_(j3 + j1 - j2) * factd_(j3 - j1 + j2) * factd_(j1 + j2 - j3) / factd_(j1 + j2 + j3 + 1)
      * factd_(j3 + m3) * factd_(j3 - m3)
      / (factd_(j1 - m1) * factd_(j1 + m1) * factd_(j2 - m2) * factd_(j2 + m2)));
  double S = 0.0;
  for (int v = vmin; v <= vmax; ++v){
    const double sgn = ((v + j2 + m2) & 1) ? -1.0 : 1.0;
    S += sgn / factd_(v) * factd_(j2 + j3 + m1 - v) * factd_(j1 - m1 + v)
         / factd_(j3 - j1 + j2 - v) / factd_(j3 + m3 - v) / factd_(v + j1 - j2 - m3);
  }
  return C * S;
}

struct QM { double re[25]; double im[25]; };
constexpr QM qmat_ce(int l){
  QM q{};
  const int n = 2*l + 1;
  const double is2 = 1.0 / csqrt_(2.0);
  for (int m = -l; m < 0; ++m){
    q.re[(l+m)*n + (l-m)] = is2;
    q.im[(l+m)*n + (l+m)] = -is2;
  }
  q.re[l*n + l] = 1.0;
  for (int m = 1; m <= l; ++m){
    const double s = (m & 1) ? -1.0 : 1.0;
    q.re[(l+m)*n + (l+m)] = s * is2;
    q.im[(l+m)*n + (l-m)] = s * is2;
  }
  const double phr = (l==0) ? 1.0 : (l==1 ? 0.0 : -1.0);
  const double phi = (l==1) ? -1.0 : 0.0;
  for (int i = 0; i < n*n; ++i){
    const double r  = q.re[i]*phr - q.im[i]*phi;
    const double im = q.re[i]*phi + q.im[i]*phr;
    q.re[i] = r; q.im[i] = im;
  }
  return q;
}

struct W3R { double v[125]; };
template<int L1,int L2,int L3>
constexpr W3R w3j_ce(){
  constexpr int n1 = 2*L1+1, n2 = 2*L2+1, n3 = 2*L3+1;
  const QM q1 = qmat_ce(L1), q2 = qmat_ce(L2), q3 = qmat_ce(L3);
  double C[n1][n2]{};
  for (int i = 0; i < n1; ++i)
    for (int k = 0; k < n2; ++k){
      const int nn = (i - L1) + (k - L2) + L3;
      C[i][k] = (nn >= 0 && nn < n3) ? su2_cg_ce(L1, i-L1, L2, k-L2, L3, nn-L3) : 0.0;
    }
  W3R out{};
  double norm = 0.0;
  for (int j = 0; j < n1; ++j)
    for (int lq = 0; lq < n2; ++lq)
      for (int m = 0; m < n3; ++m){
        double sre = 0.0;
        for (int i = 0; i < n1; ++i)
          for (int k = 0; k < n2; ++k){
            if (C[i][k] == 0.0) continue;
            const int nn = (i - L1) + (k - L2) + L3;
            const double ar = q1.re[i*n1+j],  ai = q1.im[i*n1+j];
            const double br = q2.re[k*n2+lq], bi = q2.im[k*n2+lq];
            const double cr = q3.re[nn*n3+m], ci = q3.im[nn*n3+m];
            const double abr = ar*br - ai*bi;
            const double abi = ar*bi + ai*br;
            sre += (abr*cr + abi*ci) * C[i][k];
          }
        out.v[(j*n2+lq)*n3+m] = sre;
        norm += sre*sre;
      }
  norm = csqrt_(norm);
  for (int i = 0; i < n1*n2*n3; ++i) out.v[i] /= norm;
  return out;
}

constexpr W3R W_p0  = w3j_ce<0,0,0>();
constexpr W3R W_p1  = w3j_ce<0,1,1>();
constexpr W3R W_p2  = w3j_ce<0,2,2>();
constexpr W3R W_p3  = w3j_ce<1,0,1>();
constexpr W3R W_p4  = w3j_ce<1,1,0>();
constexpr W3R W_p5  = w3j_ce<1,1,2>();
constexpr W3R W_p6  = w3j_ce<1,2,1>();
constexpr W3R W_p7  = w3j_ce<2,0,2>();
constexpr W3R W_p8  = w3j_ce<2,1,1>();
constexpr W3R W_p9  = w3j_ce<2,2,0>();
constexpr W3R W_p10 = w3j_ce<2,2,2>();

struct CoefArr { float c[363]; };
constexpr float snap_(double v){ return (v < 1e-9 && v > -1e-9) ? 0.0f : (float)v; }
constexpr CoefArr build_ck(){
  CoefArr K{};
  const W3R* W[NPATH] = {&W_p0,&W_p1,&W_p2,&W_p3,&W_p4,&W_p5,&W_p6,&W_p7,&W_p8,&W_p9,&W_p10};
  const int SZ[NPATH]  = {1,9,25,9,9,45,45,25,45,25,125};
  const int PL3[NPATH] = {0,1,2,1,0,2,1,2,1,0,2};
  const double FAN[3]  = {48.0, 64.0, 64.0};
  int off = 0;
  for (int p = 0; p < NPATH; ++p){
    const double alpha = csqrt_((double)(2*PL3[p]+1)) / csqrt_(FAN[PL3[p]]);
    for (int i = 0; i < SZ[p]; ++i) K.c[off + i] = snap_(W[p]->v[i] * alpha);
    off += SZ[p];
  }
  return K;
}
inline constexpr CoefArr CK = build_ck();

// ---------------- device helpers ----------------
typedef __attribute__((ext_vector_type(8))) short bf16x8;
typedef __attribute__((ext_vector_type(4))) float f32x4;

__device__ __forceinline__ float silu_f(float v){ return v / (1.0f + expf(-v)); }
__device__ __forceinline__ float b2f(unsigned short u){
  union { unsigned i; float f; } x; x.i = ((unsigned)u) << 16; return x.f;
}
__device__ __forceinline__ unsigned short f2b(float f){
  union { float f; unsigned i; } x; x.f = f;
  unsigned r = x.i + 0x7FFFu + ((x.i >> 16) & 1u);
  return (unsigned short)(r >> 16);
}

// ---- LDS layout (EB=16, f32 tmp, TWO CG/consume rounds sharing 20 slots):
// sh f32 [9][16] | src/dst | tmp f32 [20*16][16] (emb + emit stage alias)
// | x1 bf16 [144][18] | h bf16 [16][72].  Total 28672 B -> 5 blocks/CU at (256,5).
// (256,5): best measured config (R16). The forced min-waves raises achieved
// occupancy 43->52%, worth more than its modest spill (R16 237us vs R15 280us
// at (256,4) no-spill and R17 254us at (256,4) 3-round).
#define O_SH     0        // float idx
#define O_SD     144      // float idx (src[16], dst[16])
#define O_TPF    176      // float idx of tmp f32 [20*16][16]; emb+stage alias
#define X16_OFF  10592    // short idx of x1 bf16 [144][18]
#define H_OFF    13184    // short idx of h bf16 [16][72]
#define S_TOT    7168     // floats = 28672 B
#define XPAD 18
#define HPAD 72

__device__ __forceinline__ bf16x8 load_h_frag(const unsigned short* h16, int row, int kbase, int rg){
  return *(const bf16x8*)(h16 + row*HPAD + kbase + rg*8);
}

// ---- CG for one path: coefficient literals from CK (zeros fold away) ----
template<int D1,int D2,int D3,int SB,int COFF,int XB,int SHO>
__device__ __forceinline__ void cg_path(float* tpf,
    const float (&xv)[9], const float (&sv)[9], int u, int e)
{
  float a0[D3];
  #pragma unroll
  for (int k = 0; k < D3; ++k) a0[k] = 0.0f;
  #pragma unroll
  for (int i = 0; i < D1; ++i){
    #pragma unroll
    for (int j = 0; j < D2; ++j){
      const float p0 = xv[XB+i] * sv[SHO+j];
      #pragma unroll
      for (int k = 0; k < D3; ++k){
        const float cf = CK.c[COFF + (i*D2 + j)*D3 + k];   // compile-time constant
        if (cf != 0.0f) a0[k] = fmaf(cf, p0, a0[k]);
      }
    }
  }
  #pragma unroll
  for (int k = 0; k < D3; ++k)
    tpf[((SB + k)*16 + u)*16 + e] = a0[k];
}

// ---- consume: ONE shared body per D3-group, runtime path loop (code-size) ----
static __device__ const int gA1P[3] = {0,4,9},    gA1S[3] = {0,1,2};
static __device__ const int gA3P[4] = {1,3,6,8},  gA3S[4] = {3,6,9,12};
static __device__ const int gB5P[4] = {2,5,7,10}, gB5S[4] = {0,5,10,15};

template<int D3,int QB,int NP,int NQ>
__device__ __forceinline__ void consume_group(
    const int* __restrict__ plist, const int* __restrict__ sblist,
    const unsigned short* __restrict__ w3B, const float* __restrict__ b3,
    const float* tpf,
    const bf16x8& ha0, const bf16x8& ha1,
    int ch, int j2, int lw, int rg, float (&acc)[NQ][4])
{
  const int lane8 = (rg*16 + lw)*8;
  #pragma unroll 1
  for (int pi = 0; pi < NP; ++pi){
    const int P  = plist[pi];
    const int SB = sblist[pi];
    const unsigned short* wbase = w3B + (size_t)((P*2 + ch)*8 + j2*4)*1024 + lane8;
    const float* bcol = b3 + P*256 + ch*128 + j2*64 + lw;
    const float* tbase = tpf + (SB*16 + ch*8 + j2*4)*16 + rg*4;

    bf16x8 wf0[4], wf1[4];
    float bvv[4];
    #pragma unroll
    for (int jt = 0; jt < 4; ++jt){
      wf0[jt] = *(const bf16x8*)(wbase + jt*1024);
      wf1[jt] = *(const bf16x8*)(wbase + jt*1024 + 512);
      bvv[jt] = bcol[jt*16];
    }
    #pragma unroll
    for (int jt = 0; jt < 4; ++jt){
      f32x4 c = {bvv[jt], bvv[jt], bvv[jt], bvv[jt]};
      c = __builtin_amdgcn_mfma_f32_16x16x32_bf16(ha0, wf0[jt], c, 0, 0, 0);
      c = __builtin_amdgcn_mfma_f32_16x16x32_bf16(ha1, wf1[jt], c, 0, 0, 0);
      #pragma unroll
      for (int k = 0; k < D3; ++k){
        const f32x4 tv = *(const f32x4*)(tbase + jt*16 + k*256);
        acc[QB+k][0] = fmaf(tv[0], c[0], acc[QB+k][0]);
        acc[QB+k][1] = fmaf(tv[1], c[1], acc[QB+k][1]);
        acc[QB+k][2] = fmaf(tv[2], c[2], acc[QB+k][2]);
        acc[QB+k][3] = fmaf(tv[3], c[3], acc[QB+k][3]);
      }
    }
  }
}

template<bool TWOPASS>
__global__ __launch_bounds__(256, 5)
void e3_fused(
    const float* __restrict__ f_in, const float* __restrict__ pos,
    const int*   __restrict__ batch,
    const int*   __restrict__ esrc, const int* __restrict__ edst,
    const float* __restrict__ eshift, const float* __restrict__ cell,
    const float* __restrict__ w0, const float* __restrict__ b0,
    const float* __restrict__ b1, const float* __restrict__ b2,
    const float* __restrict__ b3, const unsigned short* __restrict__ wT,
    float* __restrict__ msg_or_out)
{
  __shared__ float S[S_TOT];
  float* tpf = S + O_TPF;
  unsigned short* x16  = (unsigned short*)S + X16_OFF;
  unsigned short* h16  = (unsigned short*)S + H_OFF;
  int* s_src = (int*)(S + O_SD);
  int* s_dst = s_src + EB;
  const int t = threadIdx.x;
  const int e0 = blockIdx.x * EB;
  const unsigned short* w3B = wT;
  const unsigned short* w1T = wT + 180224;
  const unsigned short* w2T = wT + 184320;
  float* emb = tpf;    // f32 [8][16], aliases tmp (dead before CG writes)

  // ---- geometry / SH / radial (one thread per edge) ----
  if (t < EB){
    const int eg  = e0 + t;
    const int src = esrc[eg];
    const int dst = edst[eg];
    s_src[t] = src; s_dst[t] = dst;
    const int g = batch[src];
    const float sx = eshift[eg*3+0], sy = eshift[eg*3+1], sz = eshift[eg*3+2];
    const float* cg = cell + g*9;
    float vx = pos[dst*3+0] - pos[src*3+0] + sx*cg[0] + sy*cg[3] + sz*cg[6];
    float vy = pos[dst*3+1] - pos[src*3+1] + sx*cg[1] + sy*cg[4] + sz*cg[7];
    float vz = pos[dst*3+2] - pos[src*3+2] + sx*cg[2] + sy*cg[5] + sz*cg[8];
    float r  = sqrtf(vx*vx + vy*vy + vz*vz + 1e-12f);
    float inv = 1.0f / r;
    float x = vx*inv, y = vy*inv, z = vz*inv;
    const float s3 = 1.7320508075688772f, s5 = 2.23606797749979f, s15 = 3.872983346207417f;
    S[O_SH + 0*16 + t] = 1.0f;
    S[O_SH + 1*16 + t] = s3 * y;
    S[O_SH + 2*16 + t] = s3 * z;
    S[O_SH + 3*16 + t] = s3 * x;
    S[O_SH + 4*16 + t] = s15 * x * y;
    S[O_SH + 5*16 + t] = s15 * y * z;
    S[O_SH + 6*16 + t] = 0.5f * s5 * (3.0f*z*z - 1.0f);
    S[O_SH + 7*16 + t] = s15 * x * z;
    S[O_SH + 8*16 + t] = 0.5f * s15 * (x*x - y*y);
    float xr   = fminf(fmaxf(r * (1.0f/6.0f), 0.0f), 1.0f);
    float mask = (r <= 6.0f) ? 2.8284271247461903f : 0.0f;
    #pragma unroll
    for (int b = 0; b < 8; ++b){
      float d = (xr - (float)b * (1.0f/7.0f)) * 7.0f;
      emb[b*16 + t] = mask * expf(-0.5f * d * d);
    }
  }
  __syncthreads();

  // ---- gather x1 -> bf16 transposed [c][e] ----
  for (int idx = t; idx < EB*36; idx += 256){
    const int e = idx / 36, c4 = idx - e*36;
    const float4 v = *(const float4*)(f_in + (size_t)s_src[e]*INDIM + c4*4);
    x16[(c4*4 + 0)*XPAD + e] = f2b(v.x);
    x16[(c4*4 + 1)*XPAD + e] = f2b(v.y);
    x16[(c4*4 + 2)*XPAD + e] = f2b(v.z);
    x16[(c4*4 + 3)*XPAD + e] = f2b(v.w);
  }

  const int lane = t & 63, wid = t >> 6;
  const int lw = lane & 15, rg = lane >> 4;

  // ---- MLP layer 0 (8 -> 64), VALU f32; output bf16 to h ----
  {
    const int o = t & 63, egr = t >> 6;   // each thread: 4 edges
    float s[4];
    #pragma unroll
    for (int e4 = 0; e4 < 4; ++e4) s[e4] = b0[o];
    #pragma unroll
    for (int c = 0; c < 8; ++c){
      const float wv = w0[c*64 + o];
      #pragma unroll
      for (int e4 = 0; e4 < 4; ++e4)
        s[e4] = fmaf(emb[c*16 + egr*4 + e4], wv, s[e4]);
    }
    #pragma unroll
    for (int e4 = 0; e4 < 4; ++e4) h16[(egr*4 + e4)*HPAD + o] = f2b(silu_f(s[e4]));
  }
  __syncthreads();

  // ---- MLP layers 1,2 via MFMA: C[16 e][64 o], 4 tiles over 4 waves ----
  #pragma unroll
  for (int layer = 0; layer < 2; ++layer){
    const unsigned short* wLT = layer ? w2T : w1T;
    const float* bL = layer ? b2 : b1;
    const bf16x8 a0 = load_h_frag(h16, lw, 0, rg);
    const bf16x8 a1 = load_h_frag(h16, lw, 32, rg);
    const int o = wid*16 + lw;
    const bf16x8 bf0 = *(const bf16x8*)(wLT + o*64 + rg*8);
    const bf16x8 bf1 = *(const bf16x8*)(wLT + o*64 + 32 + rg*8);
    const float bv = bL[o];
    f32x4 c = {bv, bv, bv, bv};
    c = __builtin_amdgcn_mfma_f32_16x16x32_bf16(a0, bf0, c, 0, 0, 0);
    c = __builtin_amdgcn_mfma_f32_16x16x32_bf16(a1, bf1, c, 0, 0, 0);
    __syncthreads();   // all frag reads done before overwrite
    #pragma unroll
    for (int i = 0; i < 4; ++i)
      h16[(rg*4 + i)*HPAD + wid*16 + lw] = f2b(silu_f(c[i]));
    __syncthreads();
  }

  // ---- A-fragments of final h (held through CG + consume) ----
  const int ch = wid & 1, j2 = wid >> 1;
  const bf16x8 ha0 = load_h_frag(h16, lw, 0, rg);
  const bf16x8 ha1 = load_h_frag(h16, lw, 32, rg);

  const int u_cg = t >> 4, e_cg = t & 15;

  // ================= round A: D3 in {1,3} paths, 15 tmp slots =================
  {
    float sv[9], xv[9];
    #pragma unroll
    for (int j = 0; j < 9; ++j) sv[j] = S[O_SH + j*16 + e_cg];
    #pragma unroll
    for (int ri = 0; ri < 9; ++ri)
      xv[ri] = b2f(x16[(ri*16 + u_cg)*XPAD + e_cg]);

    //      <D1,D2,D3, SB, COFF, XB, SHO>
    cg_path<1,1,1,  0,   0, 0, 0>(tpf, xv, sv, u_cg, e_cg);   // path 0
    cg_path<3,3,1,  1,  44, 1, 1>(tpf, xv, sv, u_cg, e_cg);   // path 4
    cg_path<5,5,1,  2, 213, 4, 4>(tpf, xv, sv, u_cg, e_cg);   // path 9
    cg_path<1,3,3,  3,   1, 0, 1>(tpf, xv, sv, u_cg, e_cg);   // path 1
    cg_path<3,1,3,  6,  35, 1, 0>(tpf, xv, sv, u_cg, e_cg);   // path 3
    cg_path<3,5,3,  9,  98, 1, 4>(tpf, xv, sv, u_cg, e_cg);   // path 6
    cg_path<5,3,3, 12, 168, 4, 1>(tpf, xv, sv, u_cg, e_cg);   // path 8
  }
  __syncthreads();   // tmp A complete

  float accA[4][4];
  #pragma unroll
  for (int q = 0; q < 4; ++q)
    #pragma unroll
    for (int i = 0; i < 4; ++i) accA[q][i] = 0.0f;

  consume_group<1,0,3,4>(gA1P, gA1S, w3B, b3, tpf, ha0, ha1, ch, j2, lw, rg, accA);
  consume_group<3,1,4,4>(gA3P, gA3S, w3B, b3, tpf, ha0, ha1, ch, j2, lw, rg, accA);
  __syncthreads();   // tmp A dead

  // ================= round B: D3=5 paths, 20 tmp slots =================
  {
    float sv[9], xv[9];
    #pragma unroll
    for (int j = 0; j < 9; ++j) sv[j] = S[O_SH + j*16 + e_cg];
    #pragma unroll
    for (int ri = 0; ri < 9; ++ri)
      xv[ri] = b2f(x16[(ri*16 + u_cg)*XPAD + e_cg]);

    cg_path<1,5,5,  0,  10, 0, 4>(tpf, xv, sv, u_cg, e_cg);   // path 2
    cg_path<3,3,5,  5,  53, 1, 1>(tpf, xv, sv, u_cg, e_cg);   // path 5
    cg_path<5,1,5, 10, 143, 4, 0>(tpf, xv, sv, u_cg, e_cg);   // path 7
    cg_path<5,5,5, 15, 238, 4, 4>(tpf, xv, sv, u_cg, e_cg);   // path 10
  }
  __syncthreads();   // tmp B complete

  float accB[5][4];
  #pragma unroll
  for (int q = 0; q < 5; ++q)
    #pragma unroll
    for (int i = 0; i < 4; ++i) accB[q][i] = 0.0f;

  consume_group<5,0,4,5>(gB5P, gB5S, w3B, b3, tpf, ha0, ha1, ch, j2, lw, rg, accB);
  __syncthreads();   // tmp dead; staging region free

  // ---- emit: 4-wave sequential reduction into stage, then coalesced store ----
  if (TWOPASS){
    float* stage = tpf;   // [16 e][144] f32, aliases tmp
    if (wid == 0){
      #pragma unroll
      for (int q = 0; q < 4; ++q)
        #pragma unroll
        for (int i = 0; i < 4; ++i)
          stage[(rg*4 + i)*INDIM + q*16 + lw] = accA[q][i];
      #pragma unroll
      for (int q = 0; q < 5; ++q)
        #pragma unroll
        for (int i = 0; i < 4; ++i)
          stage[(rg*4 + i)*INDIM + (q + 4)*16 + lw] = accB[q][i];
    }
    __syncthreads();
    #pragma unroll
    for (int w = 1; w < 4; ++w){
      if (wid == w){
        #pragma unroll
        for (int q = 0; q < 4; ++q)
          #pragma unroll
          for (int i = 0; i < 4; ++i)
            stage[(rg*4 + i)*INDIM + q*16 + lw] += accA[q][i];
        #pragma unroll
        for (int q = 0; q < 5; ++q)
          #pragma unroll
          for (int i = 0; i < 4; ++i)
            stage[(rg*4 + i)*INDIM + (q + 4)*16 + lw] += accB[q][i];
      }
      __syncthreads();
    }
    for (int idx = t; idx < EB*36; idx += 256){
      const int e = idx / 36, c4 = idx - e*36;
      *(float4*)(msg_or_out + (size_t)(e0 + e)*INDIM + c4*4) =
          *(const float4*)(stage + e*INDIM + c4*4);
    }
  } else {
    #pragma unroll
    for (int i = 0; i < 4; ++i){
      const int e = rg*4 + i;
      float* op = msg_or_out + (size_t)s_dst[e]*INDIM + lw;
      #pragma unroll
      for (int q = 0; q < 4; ++q) atomicAdd(op + q*16, accA[q][i]);
      #pragma unroll
      for (int q = 0; q < 5; ++q) atomicAdd(op + (q + 4)*16, accB[q][i]);
    }
  }
}

// ---------------- weight conversion ----------------
__device__ __forceinline__ unsigned short f2b_dev(float f){
  union { float f; unsigned i; } x; x.f = f;
  unsigned r = x.i + 0x7FFFu + ((x.i >> 16) & 1u);
  return (unsigned short)(r >> 16);
}
__global__ __launch_bounds__(256)
void w_cvt(const float* __restrict__ w3, const float* __restrict__ w1,
           const float* __restrict__ w2, unsigned short* __restrict__ wT){
  const int id = blockIdx.x*256 + threadIdx.x;
  if (id < 180224){
    const int tile = id >> 10, rem = id & 1023;
    const int P = tile >> 4, ch = (tile >> 3) & 1, jq = tile & 7;
    const int half = rem >> 9, rg = (rem >> 7) & 3, lw = (rem >> 3) & 15, kk = rem & 7;
    const int n = P*256 + ch*128 + jq*16 + lw;
    const int k = half*32 + rg*8 + kk;
    wT[id] = f2b_dev(w3[(size_t)k*2816 + n]);
  } else if (id < 184320){
    const int j = id - 180224; const int o = j >> 6, c = j & 63;
    wT[id] = f2b_dev(w1[c*64 + o]);
  } else if (id < 188416){
    const int j = id - 184320; const int o = j >> 6, c = j & 63;
    wT[id] = f2b_dev(w2[c*64 + o]);
  }
}

// ---------------- scatter infrastructure ----------------
__global__ __launch_bounds__(256)
void e3_hist(const int* __restrict__ edst, int* __restrict__ cnt){
  int e = blockIdx.x*256 + threadIdx.x;
  if (e < NEDGES) atomicAdd(&cnt[edst[e]], 1);
}

__global__ __launch_bounds__(1024)
void e3_scan(const int* __restrict__ cnt, int* __restrict__ offs, int* __restrict__ cursor, int n){
  __shared__ int buf[1024];
  __shared__ int carry;
  const int t = threadIdx.x;
  if (t == 0) carry = 0;
  __syncthreads();
  for (int base = 0; base < n; base += 1024){
    int v = (base + t < n) ? cnt[base + t] : 0;
    buf[t] = v;
    __syncthreads();
    for (int d = 1; d < 1024; d <<= 1){
      int x = (t >= d) ? buf[t - d] : 0;
      __syncthreads();
      buf[t] += x;
      __syncthreads();
    }
    const int base_c = carry;
    if (base + t < n){
      const int ex = base_c + buf[t] - v;
      offs[base + t]   = ex;
      cursor[base + t] = ex;
    }
    __syncthreads();
    if (t == 1023) carry = base_c + buf[1023];
    __syncthreads();
  }
  if (t == 0) offs[n] = carry;
}

__global__ __launch_bounds__(256)
void e3_fill(const int* __restrict__ edst, int* __restrict__ cursor, int* __restrict__ eidx){
  int e = blockIdx.x*256 + threadIdx.x;
  if (e < NEDGES){
    int pos = atomicAdd(&cursor[edst[e]], 1);
    eidx[pos] = e;
  }
}

__global__ __launch_bounds__(192)
void e3_reduce(const float* __restrict__ msg, const int* __restrict__ offs,
               const int* __restrict__ eidx, float* __restrict__ out){
  const int nid = blockIdx.x;
  const int t = threadIdx.x;
  if (t >= 144) return;
  const int beg = offs[nid], end = offs[nid + 1];
  float a0 = 0.f, a1 = 0.f, a2 = 0.f, a3 = 0.f;
  int i = beg;
  for (; i + 4 <= end; i += 4){
    const int i0 = eidx[i], i1 = eidx[i+1], i2 = eidx[i+2], i3 = eidx[i+3];
    a0 += msg[(size_t)i0*INDIM + t];
    a1 += msg[(size_t)i1*INDIM + t];
    a2 += msg[(size_t)i2*INDIM + t];
    a3 += msg[(size_t)i3*INDIM + t];
  }
  for (; i < end; ++i) a0 += msg[(size_t)eidx[i]*INDIM + t];
  const float deg = (float)(end - beg);
  out[(size_t)nid*INDIM + t] = (a0 + a1 + a2 + a3) / fmaxf(deg, 1.0f);
}

__global__ __launch_bounds__(256)
void e3_div(float* __restrict__ out, const int* __restrict__ cnt, int n){
  int i = blockIdx.x*256 + threadIdx.x;
  if (i < n){
    float c = (float)cnt[i / INDIM];
    out[i] /= fmaxf(c, 1.0f);
  }
}

extern "C" void kernel_launch(void* const* d_in, const int* in_sizes, int n_in,
                              void* d_out, int out_size, void* d_ws, size_t ws_size,
                              hipStream_t stream)
{
  const float* f_in   = (const float*)d_in[0];
  const float* pos    = (const float*)d_in[1];
  const int*   batch  = (const int*)  d_in[3];
  const int*   esrc   = (const int*)  d_in[4];
  const int*   edst   = (const int*)  d_in[5];
  const float* eshift = (const float*)d_in[6];
  const float* cell   = (const float*)d_in[7];
  const float* w0 = (const float*)d_in[8];  const float* b0 = (const float*)d_in[9];
  const float* w1 = (const float*)d_in[10]; const float* b1 = (const float*)d_in[11];
  const float* w2 = (const float*)d_in[12]; const float* b2 = (const float*)d_in[13];
  const float* w3 = (const float*)d_in[14]; const float* b3 = (const float*)d_in[15];
  float* out = (float*)d_out;

  const size_t need = (1u << 20) + (size_t)NEDGES * INDIM * sizeof(float);
  const bool twopass = ws_size >= need;

  if (twopass){
    int* cnt_i  = (int*)d_ws;
    int* offs   = (int*)d_ws + 16384;
    int* cursor = (int*)d_ws + 32768;
    int* eidx   = (int*)d_ws + 49152;
    float* msg  = (float*)((char*)d_ws + (1u << 20));
    unsigned short* wT = (unsigned short*)d_out;   // dead until e3_reduce overwrites

    w_cvt<<<736, 256, 0, stream>>>(w3, w1, w2, wT);
    hipMemsetAsync(cnt_i, 0, 10240 * sizeof(int), stream);
    e3_hist<<<(NEDGES + 255)/256, 256, 0, stream>>>(edst, cnt_i);
    e3_scan<<<1, 1024, 0, stream>>>(cnt_i, offs, cursor, NNODES);
    e3_fill<<<(NEDGES + 255)/256, 256, 0, stream>>>(edst, cursor, eidx);
    e3_fused<true><<<NEDGES/EB, 256, 0, stream>>>(
        f_in, pos, batch, esrc, edst, eshift, cell,
        w0, b0, b1, b2, b3, wT, msg);
    e3_reduce<<<NNODES, 192, 0, stream>>>(msg, offs, eidx, out);
  } else {
    unsigned short* wT = (unsigned short*)d_ws;            // 376832 B
    int* cnt_i = (int*)((char*)d_ws + 376832);

    w_cvt<<<736, 256, 0, stream>>>(w3, w1, w2, wT);
    hipMemsetAsync(cnt_i, 0, NNODES * sizeof(int), stream);
    e3_hist<<<(NEDGES + 255)/256, 256, 0, stream>>>(edst, cnt_i);
    hipMemsetAsync(d_out, 0, (size_t)out_size * sizeof(float), stream);
    e3_fused<false><<<NEDGES/EB, 256, 0, stream>>>(
        f_in, pos, batch, esrc, edst, eshift, cell,
        w0, b0, b1, b2, b3, wT, out);
    e3_div<<<(out_size + 255)/256, 256, 0, stream>>>(out, cnt_i, out_size);
  }
}